// Round 11
// baseline (361.125 us; speedup 1.0000x reference)
//
#include <hip/hip_runtime.h>

typedef __bf16 bf16x8 __attribute__((ext_vector_type(8)));
typedef float f32x4 __attribute__((ext_vector_type(4)));

typedef __attribute__((address_space(1))) void gvoid;
typedef __attribute__((address_space(3))) void lvoid;

__device__ __forceinline__ void gl_lds16(const void* g, void* l) {
    __builtin_amdgcn_global_load_lds((gvoid*)g, (lvoid*)l, 16, 0, 0);
}

// NaN/inf scrub for epilogues only.
__device__ __forceinline__ float fin(float v) {
    v = (v == v) ? v : 0.f;
    return fminf(fmaxf(v, -3.0e38f), 3.0e38f);
}

__device__ __forceinline__ bf16x8 cvt8(float4 a, float4 b) {
    bf16x8 r;
    r[0] = (__bf16)a.x; r[1] = (__bf16)a.y; r[2] = (__bf16)a.z; r[3] = (__bf16)a.w;
    r[4] = (__bf16)b.x; r[5] = (__bf16)b.y; r[6] = (__bf16)b.z; r[7] = (__bf16)b.w;
    return r;
}

__device__ __forceinline__ void cvt_range(const float* __restrict__ in,
                                          __bf16* __restrict__ out, int i) {
    const float4* p = (const float4*)in + (size_t)i * 2;
    ((bf16x8*)out)[i] = cvt8(p[0], p[1]);
}

// ---------------------------------------------------------------------------
// prep: fused cvt(x)+gate, cvt(w_qkv), rope table. (unchanged from round 8)
// ---------------------------------------------------------------------------
__global__ __launch_bounds__(256) void prep_kernel(const float* __restrict__ x,
                                                   const float* __restrict__ wqkv,
                                                   __bf16* __restrict__ xb,
                                                   __bf16* __restrict__ wqb,
                                                   const float* __restrict__ wg,
                                                   const float* __restrict__ bg,
                                                   float* __restrict__ gate,
                                                   float2* __restrict__ ropet) {
    __shared__ float gp[4][16];
    int bid = blockIdx.x, tid = threadIdx.x;
    if (bid < 4096) {
        // ---- one (b,s) row: cvt + gate ----
        int lane = tid & 63, wave = tid >> 6;
        const float4* xr = (const float4*)(x + (size_t)bid * 2048);
        float4 p0 = xr[tid * 2], p1 = xr[tid * 2 + 1];
        ((bf16x8*)xb)[bid * 256 + tid] = cvt8(p0, p1);
#pragma unroll
        for (int h = 0; h < 16; ++h) {
            const float4* wr = (const float4*)(wg + (size_t)h * 2048);
            float4 w0 = wr[tid * 2], w1 = wr[tid * 2 + 1];
            float acc = p0.x * w0.x + p0.y * w0.y + p0.z * w0.z + p0.w * w0.w +
                        p1.x * w1.x + p1.y * w1.y + p1.z * w1.z + p1.w * w1.w;
#pragma unroll
            for (int m = 1; m < 64; m <<= 1) acc += __shfl_xor(acc, m);
            if (lane == 0) gp[wave][h] = acc;
        }
        __syncthreads();
        if (tid < 16) {
            int s = bid & 2047, b = bid >> 11;
            float z = gp[0][tid] + gp[1][tid] + gp[2][tid] + gp[3][tid] + bg[tid];
            gate[((size_t)b * 16 + tid) * 2048 + s] = 1.f / (1.f + __expf(-z));
        }
        return;
    }
    if (bid < 7168) {
        cvt_range(wqkv, wqb, (bid - 4096) * 256 + tid);
        return;
    }
    // ---- rope table: idx = s*64 + d0 ----
    int idx = (bid - 7168) * 256 + tid;
    int s = idx >> 6, d0 = idx & 63;
    float freq = (float)s * __expf(-(float)d0 * (9.2103403719761836f / 64.0f));
    ropet[idx] = make_float2(cosf(freq), sinf(freq));
}

// ---------------------------------------------------------------------------
// 8-phase GEMM (m201 template) + T1 XCD swizzle + fused K-normrope epilogue.
//
// ROUND-10 FIX: the fragment-read swizzle. The old abase
// (mrow*64+quad*16 ^ ((mrow&8)<<2)) put every consecutive-8-lane group on
// bank-quads {0,4,0,4,...} — a 4-8 way conflict on EVERY ds_read_b128 in the
// hot loop (measured-equivalent: both gemms ran at ~600 TF = m201/2.94 =
// m136's 8-way factor). New involution: reader (quad,mrow) takes slot
// mrow*4 + (quad ^ ((mrow>>1)&3)) within each 1024B subtile -> each 8-lane
// cycle-group covers 8 DISTINCT bank-quads (conflict-free). Staging keeps
// the linear gl_lds dest and applies the inverse on the global source:
// slot p holds k-group g = (p&3) ^ ((p>>3)&3). Round trip: g = q ✓.
// ---------------------------------------------------------------------------
template <int WMT, int WNT, int EPI, typename TC>
__global__ __launch_bounds__(512) void gemm8p(const __bf16* __restrict__ A,
                                              const __bf16* __restrict__ B,
                                              TC* __restrict__ C,
                                              int M, int N, int K,
                                              const float* __restrict__ kw,
                                              const float2* __restrict__ ropet,
                                              __bf16* __restrict__ Kx) {
    constexpr int BM = WMT * 32;   // WARPS_M = 2
    constexpr int BN = WNT * 64;   // WARPS_N = 4
    constexpr int LA = BM / 128;   // gl_lds16 per thread per A half-tile
    constexpr int LB = BN / 128;
    constexpr int VMC = 2 * LA + LB;

    __shared__ __align__(16) __bf16 As[2][BM * 64];
    __shared__ __align__(16) __bf16 Bs[2][BN * 64];

    const int tid = threadIdx.x;
    const int lane = tid & 63, wave = tid >> 6;
    const int wm = wave >> 2, wn = wave & 3;
    const int quad = lane >> 4, mrow = lane & 15;

    // T1 bijective XCD swizzle (nwg % 8 == 0 for both instantiations).
    const int nbx = gridDim.x;
    const int nwg = nbx * gridDim.y;
    const int orig = (int)blockIdx.y * nbx + (int)blockIdx.x;
    const int wg = (orig & 7) * (nwg >> 3) + (orig >> 3);
    const size_t row0 = (size_t)(wg / nbx) * BM;
    const size_t col0 = (size_t)(wg % nbx) * BN;

    // Inverse-swizzled global source offsets for linear gl_lds staging.
    size_t sA[LA], sB[LB];
    int dA[LA], dB[LB];
#pragma unroll
    for (int c = 0; c < LA; ++c) {
        int q = c * 512 + tid;
        int a = q * 16;                       // linear LDS byte offset
        int p = (a >> 4) & 63;                // slot within 1024B subtile
        int rowl = (a >> 11) * 16 + (p >> 2);
        int g = (p & 3) ^ ((p >> 3) & 3);     // logical k-group at this slot
        int col = ((a >> 10) & 1) * 32 + g * 8;
        sA[c] = (size_t)rowl * K + col;
        dA[c] = q * 8;
    }
#pragma unroll
    for (int c = 0; c < LB; ++c) {
        int q = c * 512 + tid;
        int a = q * 16;
        int p = (a >> 4) & 63;
        int rowl = (a >> 11) * 16 + (p >> 2);
        int g = (p & 3) ^ ((p >> 3) & 3);
        int col = ((a >> 10) & 1) * 32 + g * 8;
        sB[c] = (size_t)rowl * K + col;
        dB[c] = q * 8;
    }

    const __bf16* Ag = A + row0 * K;
    const __bf16* Bg = B + col0 * K;

    f32x4 acc[WMT][WNT];
#pragma unroll
    for (int i = 0; i < WMT; ++i)
#pragma unroll
        for (int j = 0; j < WNT; ++j) acc[i][j] = (f32x4){0.f, 0.f, 0.f, 0.f};

    // Conflict-free per-lane ds_read base (slot = mrow*4 + quad^((mrow>>1)&3)).
    const int abase = mrow * 64 + ((quad ^ ((mrow >> 1) & 3)) * 16);

    bf16x8 af[WMT / 2][2], bf[WNT / 2][2];

#define STA8(buf, h, kt)                                                        \
    _Pragma("unroll") for (int c = 0; c < LA; ++c)                              \
        gl_lds16(Ag + (size_t)(h) * (BM / 2) * K + (size_t)(kt) * 64 + sA[c],   \
                 &As[buf][(h) * (BM / 2) * 64 + dA[c]])

#define STB8(buf, h, kt)                                                        \
    _Pragma("unroll") for (int c = 0; c < LB; ++c)                              \
        gl_lds16(Bg + (size_t)(h) * (BN / 2) * K + (size_t)(kt) * 64 + sB[c],   \
                 &Bs[buf][(h) * (BN / 2) * 64 + dB[c]])

#define LDA8(buf, mh)                                                           \
    _Pragma("unroll") for (int m2 = 0; m2 < WMT / 2; ++m2)                      \
    _Pragma("unroll") for (int s = 0; s < 2; ++s)                               \
        af[m2][s] = *(const bf16x8*)((const char*)&As[buf][0] +                 \
            ((((mh) * (WMT / 2) + m2) * 2 + wm) * 2 + s) * 1024 + abase)

#define LDB8(buf, nh)                                                           \
    _Pragma("unroll") for (int n2 = 0; n2 < WNT / 2; ++n2)                      \
    _Pragma("unroll") for (int s = 0; s < 2; ++s)                               \
        bf[n2][s] = *(const bf16x8*)((const char*)&Bs[buf][0] +                 \
            ((((nh) * (WNT / 2) + n2) * 4 + wn) * 2 + s) * 1024 + abase)

#define MMA8(mh, nh)                                                            \
    _Pragma("unroll") for (int m2 = 0; m2 < WMT / 2; ++m2)                      \
    _Pragma("unroll") for (int n2 = 0; n2 < WNT / 2; ++n2)                      \
    _Pragma("unroll") for (int s = 0; s < 2; ++s)                               \
        acc[(mh) * (WMT / 2) + m2][(nh) * (WNT / 2) + n2] =                     \
            __builtin_amdgcn_mfma_f32_16x16x32_bf16(                            \
                af[m2][s], bf[n2][s],                                           \
                acc[(mh) * (WMT / 2) + m2][(nh) * (WNT / 2) + n2], 0, 0, 0)

#define BAR8 __builtin_amdgcn_s_barrier()

#define WAITVM                                                                  \
    do {                                                                        \
        if constexpr (VMC == 6)                                                 \
            asm volatile("s_waitcnt vmcnt(6)" ::: "memory");                    \
        else                                                                    \
            asm volatile("s_waitcnt vmcnt(4)" ::: "memory");                    \
    } while (0)

#define PHASE_TAIL(mh, nh)                                                      \
    __builtin_amdgcn_s_barrier();                                               \
    asm volatile("s_waitcnt lgkmcnt(0)" ::: "memory");                          \
    __builtin_amdgcn_sched_barrier(0);                                          \
    __builtin_amdgcn_s_setprio(1);                                              \
    MMA8(mh, nh);                                                               \
    __builtin_amdgcn_s_setprio(0)

    const int NT = K / 64;

    STA8(0, 0, 0);
    STB8(0, 0, 0);
    STA8(0, 1, 0);
    STB8(0, 1, 0);
    STA8(1, 0, 1);
    STB8(1, 1, 1);
    STA8(1, 1, 1);
    WAITVM;
    BAR8;

    for (int i = 0; i < NT / 2; ++i) {
        const int u = 2 * i;
        const int k2 = (u + 2 < NT) ? u + 2 : NT - 1;
        const int k3 = (u + 3 < NT) ? u + 3 : NT - 1;
        // ---- tile u (buf0) ----
        LDA8(0, 0); LDB8(0, 0); STB8(1, 0, u + 1);
        PHASE_TAIL(0, 0); BAR8;
        LDB8(0, 1); STA8(0, 0, k2);
        PHASE_TAIL(0, 1); BAR8;
        LDA8(0, 1); STB8(0, 1, k2);
        PHASE_TAIL(1, 1); BAR8;
        LDB8(0, 0); STA8(0, 1, k2);
        PHASE_TAIL(1, 0); WAITVM; BAR8;
        // ---- tile u+1 (buf1) ----
        LDA8(1, 0); LDB8(1, 0); STB8(0, 0, k2);
        PHASE_TAIL(0, 0); BAR8;
        LDB8(1, 1); STA8(1, 0, k3);
        PHASE_TAIL(0, 1); BAR8;
        LDA8(1, 1); STB8(1, 1, k3);
        PHASE_TAIL(1, 1); BAR8;
        LDB8(1, 0); STA8(1, 1, k3);
        PHASE_TAIL(1, 0); WAITVM; BAR8;
    }
    asm volatile("s_waitcnt vmcnt(0)" ::: "memory");

#undef STA8
#undef STB8
#undef LDA8
#undef LDB8
#undef MMA8
#undef BAR8
#undef WAITVM
#undef PHASE_TAIL

    if constexpr (EPI) {
        int xblk = (int)(col0 >> 8);
        if (xblk == 8 || xblk == 9) {
            // ---- fused K normrope -> Kx (fp32-accurate rmsnorm) ----
            __syncthreads();  // LDS quiescent; reuse As for the reduce
            float* sums = (float*)&As[0][0];
            const int d0 = wn * 16 + mrow;
#pragma unroll
            for (int mt = 0; mt < WMT; ++mt)
#pragma unroll
                for (int t = 0; t < 2; ++t) {
                    f32x4 p;
#pragma unroll
                    for (int r = 0; r < 4; ++r)
                        p[r] = acc[mt][2 * t][r] * acc[mt][2 * t][r] +
                               acc[mt][2 * t + 1][r] * acc[mt][2 * t + 1][r];
#pragma unroll
                    for (int m = 1; m < 16; m <<= 1)
#pragma unroll
                        for (int r = 0; r < 4; ++r) p[r] += __shfl_xor(p[r], m);
                    if (mrow == 0) {
                        int idx = ((((wm * 8 + mt) * 4 + quad) * 2 + t) * 4 + wn) * 4;
#pragma unroll
                        for (int r = 0; r < 4; ++r) sums[idx + r] = p[r];
                    }
                }
            __syncthreads();
            float w1 = kw[d0], w2 = kw[d0 + 64];
#pragma unroll
            for (int mt = 0; mt < WMT; ++mt) {
                int rbase = (int)row0 + (mt * 2 + wm) * 16 + quad * 4;
#pragma unroll
                for (int t = 0; t < 2; ++t) {
                    int ib = (((wm * 8 + mt) * 4 + quad) * 2 + t) * 16;
                    f32x4 sv = *(const f32x4*)&sums[ib] + *(const f32x4*)&sums[ib + 4] +
                               *(const f32x4*)&sums[ib + 8] + *(const f32x4*)&sums[ib + 12];
                    int kvh = (xblk - 8) * 2 + t;
#pragma unroll
                    for (int r = 0; r < 4; ++r) {
                        int row = rbase + r;
                        int s_ = row & 2047, b_ = row >> 11;
                        float inv = rsqrtf(sv[r] * (1.0f / 128.0f) + 1e-5f);
                        float2 cs = ropet[s_ * 64 + d0];
                        float y1 = acc[mt][2 * t][r] * inv * w1;
                        float y2 = acc[mt][2 * t + 1][r] * inv * w2;
                        __bf16* dst = Kx + (((size_t)(b_ * 4 + kvh) * 2048 + s_) << 7);
                        dst[d0] = (__bf16)(y1 * cs.x - y2 * cs.y);
                        dst[d0 + 64] = (__bf16)(y1 * cs.y + y2 * cs.x);
                    }
                }
            }
            return;  // K never written to qkv
        }
    }

#pragma unroll
    for (int mt = 0; mt < WMT; ++mt)
#pragma unroll
        for (int nt = 0; nt < WNT; ++nt)
#pragma unroll
            for (int r = 0; r < 4; ++r) {
                size_t row = row0 + (mt * 2 + wm) * 16 + quad * 4 + r;
                size_t col = col0 + (nt * 4 + wn) * 16 + mrow;
                C[row * N + col] = (TC)fin(acc[mt][nt][r]);
            }
}

// ---------------------------------------------------------------------------
// mid: fused Q-normrope + vtrans. Blocks [0,16384): Q heads only (K handled
// by the gemm epilogue); [16384,16896): vtrans.
// ---------------------------------------------------------------------------
#define SCALE_LOG2E 0.12751666797152713f

__global__ __launch_bounds__(256) void mid_kernel(const __bf16* __restrict__ qkv,
                                                  const float* __restrict__ qw,
                                                  const float2* __restrict__ ropet,
                                                  __bf16* __restrict__ Q,
                                                  __bf16* __restrict__ Vt) {
    __shared__ __align__(16) __bf16 tile[64][72];
    int bid = blockIdx.x, t = threadIdx.x;
    if (bid < 16384) {
        // ---- RMSNorm + RoPE, Q heads (pre-scaled for exp2 softmax) ----
        int wid = bid * 4 + (t >> 6);
        int lane = t & 63;
        int head = wid & 15;
        int bs = wid >> 4;
        int s = bs & 2047, b = bs >> 11;
        const __bf16* src = qkv + (size_t)bs * 3072 + head * 128;
        __bf16* dst = Q + ((size_t)(b * 16 + head) * 2048 + s) * 128;
        float x1 = (float)src[lane], x2 = (float)src[lane + 64];
        float ss = x1 * x1 + x2 * x2;
#pragma unroll
        for (int m = 1; m < 64; m <<= 1) ss += __shfl_xor(ss, m);
        float inv = rsqrtf(ss * (1.0f / 128.0f) + 1e-5f);
        float y1 = x1 * inv * qw[lane];
        float y2 = x2 * inv * qw[lane + 64];
        float2 cs = ropet[s * 64 + lane];
        dst[lane] = (__bf16)((y1 * cs.x - y2 * cs.y) * SCALE_LOG2E);
        dst[lane + 64] = (__bf16)((y1 * cs.y + y2 * cs.x) * SCALE_LOG2E);
        return;
    }
    // ---- V transpose ----
    int v = bid - 16384;
    int st0 = (v & 31) * 64;
    int dblk = (v >> 5) & 1;
    int bz = v >> 6;
    int b = bz >> 2, kv = bz & 3;
    const __bf16* src = qkv + (size_t)(b * 2048 + st0) * 3072 + 2560 + kv * 128 + dblk * 64;
#pragma unroll
    for (int it = 0; it < 2; ++it) {
        int row = it * 32 + (t >> 3);
        int ch = t & 7;
        *(bf16x8*)&tile[row][ch * 8] = *(const bf16x8*)(src + (size_t)row * 3072 + ch * 8);
    }
    __syncthreads();
    __bf16* dst = Vt + ((size_t)(b * 4 + kv) * 128 + dblk * 64) * 2048 + st0;
#pragma unroll
    for (int it = 0; it < 2; ++it) {
        int drow = it * 32 + (t >> 3);
        int sch = t & 7;
        bf16x8 vv;
#pragma unroll
        for (int j = 0; j < 8; ++j) vv[j] = tile[sch * 8 + j][drow];
        *(bf16x8*)(dst + (size_t)drow * 2048 + sch * 8) = vv;
    }
}

// ---------------------------------------------------------------------------
// Flash attention v8 (unchanged): key-split-in-block, 8 waves, backfill,
// conflict-free merge, w_o cvt grid tail.
// ---------------------------------------------------------------------------
#define FIXED_M 20.0f

#define MFMA16(a, b, c) __builtin_amdgcn_mfma_f32_16x16x32_bf16(a, b, c, 0, 0, 0)

template <int MODE>  // 0: both full; 1: h0 diag + h1 full; 2: h1 diag only
__device__ __forceinline__ void attn_step(const __bf16* Kl, const __bf16* Vl,
                                          int ws, int quad, int mrow,
                                          const bf16x8* aq0, const bf16x8* aq1,
                                          f32x4* o0, f32x4* o1,
                                          float* l0, float* l1,
                                          __bf16* Pw) {
    f32x4 sc0[4], sc1[4];
    __builtin_amdgcn_s_setprio(1);
#pragma unroll
    for (int jt = 0; jt < 4; ++jt) {
        f32x4 s0 = (f32x4){0.f, 0.f, 0.f, 0.f};
        f32x4 s1 = (f32x4){0.f, 0.f, 0.f, 0.f};
#pragma unroll
        for (int dt = 0; dt < 4; ++dt) {
            bf16x8 bk = *(const bf16x8*)&Kl[((dt * 4 + quad) * 64 + jt * 16 + mrow) * 8];
            if (MODE < 2) s0 = MFMA16(aq0[dt], bk, s0);
            s1 = MFMA16(aq1[dt], bk, s1);
        }
        sc0[jt] = s0;
        sc1[jt] = s1;
    }
    __builtin_amdgcn_s_setprio(0);

    if (MODE == 1) {
        int rloc = ws * 16 + quad * 4;
#pragma unroll
        for (int jt = 0; jt < 4; ++jt)
#pragma unroll
            for (int r = 0; r < 4; ++r)
                if (jt * 16 + mrow > rloc + r) sc0[jt][r] = -1e30f;
    }
    if (MODE == 2) {
        int rloc = ws * 16 + quad * 4;
#pragma unroll
        for (int jt = 0; jt < 4; ++jt)
#pragma unroll
            for (int r = 0; r < 4; ++r)
                if (jt * 16 + mrow > rloc + r) sc1[jt][r] = -1e30f;
    }

    // Streaming softmax through the SHARED per-wave P buffer (h0 then h1;
    // same-wave DS ops execute in order, so the WAR on Pw is safe).
    bf16x8 ap0[2], ap1[2];
    if (MODE < 2) {
#pragma unroll
        for (int r = 0; r < 4; ++r) {
            float ps = 0.f;
#pragma unroll
            for (int jt = 0; jt < 4; ++jt) {
                float pv = exp2f(sc0[jt][r] - FIXED_M);
                ps += pv;
                int k = jt * 16 + mrow;
                Pw[((k >> 3) * 16 + quad * 4 + r) * 8 + (k & 7)] = (__bf16)pv;
            }
#pragma unroll
            for (int off = 1; off < 16; off <<= 1) ps += __shfl_xor(ps, off);
            l0[r] += ps;
        }
#pragma unroll
        for (int ks = 0; ks < 2; ++ks)
            ap0[ks] = *(const bf16x8*)&Pw[((ks * 4 + quad) * 16 + mrow) * 8];
    }
#pragma unroll
    for (int r = 0; r < 4; ++r) {
        float ps = 0.f;
#pragma unroll
        for (int jt = 0; jt < 4; ++jt) {
            float pv = exp2f(sc1[jt][r] - FIXED_M);
            ps += pv;
            int k = jt * 16 + mrow;
            Pw[((k >> 3) * 16 + quad * 4 + r) * 8 + (k & 7)] = (__bf16)pv;
        }
#pragma unroll
        for (int off = 1; off < 16; off <<= 1) ps += __shfl_xor(ps, off);
        l1[r] += ps;
    }
#pragma unroll
    for (int ks = 0; ks < 2; ++ks)
        ap1[ks] = *(const bf16x8*)&Pw[((ks * 4 + quad) * 16 + mrow) * 8];

    __builtin_amdgcn_s_setprio(1);
#pragma unroll
    for (int d2 = 0; d2 < 8; ++d2)
#pragma unroll
        for (int ks = 0; ks < 2; ++ks) {
            bf16x8 bv = *(const bf16x8*)&Vl[((ks * 4 + quad) * 128 + d2 * 16 + mrow) * 8];
            if (MODE < 2) o0[d2] = MFMA16(ap0[ks], bv, o0[d2]);
            o1[d2] = MFMA16(ap1[ks], bv, o1[d2]);
        }
    __builtin_amdgcn_s_setprio(0);
}

__global__ __launch_bounds__(512, 2) void attn_kernel(const __bf16* __restrict__ Q,
                                                      const __bf16* __restrict__ Kx,
                                                      const __bf16* __restrict__ Vt,
                                                      const float* __restrict__ gate,
                                                      __bf16* __restrict__ O,
                                                      const float* __restrict__ wo,
                                                      __bf16* __restrict__ wob) {
    __shared__ __align__(16) __bf16 Kl[2][2][64 * 128];  // [stream][buf]
    __shared__ __align__(16) __bf16 Vl[2][2][128 * 64];  // [stream][buf]
    __shared__ __align__(16) __bf16 Pl[8][1024];
    int tid = threadIdx.x, lane = tid & 63, wave = tid >> 6;

    if (blockIdx.x >= 512) {
        // ---- w_o cvt tail: backfills CUs as attn blocks drain ----
        cvt_range(wo, wob, ((int)blockIdx.x - 512) * 512 + tid);
        return;
    }

    int ws = wave & 3, st = wave >> 2;  // row-group, stream
    int quad = lane >> 4, mrow = lane & 15;
    __bf16* Pw = &Pl[wave][0];

    int idx = blockIdx.x;
    int qb = 15 - (idx >> 5);  // longest items dispatch first (backfill)
    int h = idx & 15, b = (idx >> 4) & 1;
    int kvh = h >> 2;

    // Staging: threads 0-255 stage the even-stream tile, 256-511 the odd.
    int sst = tid >> 8, lt = tid & 255;
    const __bf16* kbase = Kx + (size_t)(b * 4 + kvh) * 2048 * 128 + (lt & 63) * 128 + (lt >> 6) * 8;
    const __bf16* vbase = Vt + (size_t)(b * 4 + kvh) * 128 * 2048 + (lt & 127) * 2048 + (lt >> 7) * 8;
    int ldst = lt * 8;

    auto STAGE = [&](int buf, int tile) {
        const __bf16* kp = kbase + (size_t)tile * 8192;
        const __bf16* vp = vbase + (size_t)tile * 64;
#pragma unroll
        for (int c = 0; c < 4; ++c) gl_lds16(kp + 32 * c, &Kl[sst][buf][ldst + 2048 * c]);
#pragma unroll
        for (int c = 0; c < 4; ++c) gl_lds16(vp + 16 * c, &Vl[sst][buf][ldst + 2048 * c]);
    };

    STAGE(0, sst);  // even stream: tile 0; odd stream: tile 1

    const __bf16* Qh = Q + ((size_t)(b * 16 + h) * 2048 + qb * 128 + ws * 16 + mrow) * 128;
    bf16x8 aq0[4], aq1[4];
#pragma unroll
    for (int dt = 0; dt < 4; ++dt) {
        aq0[dt] = *(const bf16x8*)(Qh + dt * 32 + quad * 8);
        aq1[dt] = *(const bf16x8*)(Qh + 8192 + dt * 32 + quad * 8);
    }

    f32x4 o0[8], o1[8];
#pragma unroll
    for (int d2 = 0; d2 < 8; ++d2) {
        o0[d2] = (f32x4){0.f, 0.f, 0.f, 0.f};
        o1[d2] = (f32x4){0.f, 0.f, 0.f, 0.f};
    }
    float l0[4] = {0.f, 0.f, 0.f, 0.f}, l1[4] = {0.f, 0.f, 0.f, 0.f};

    __syncthreads();  // tiles 0,1 visible (barrier drains gl_lds)

    int cur = 0;
    for (int kt = 0; kt < qb; ++kt) {
        STAGE(cur ^ 1, 2 * (kt + 1) + sst);  // prefetch both streams' next
        attn_step<0>(Kl[st][cur], Vl[st][cur], ws, quad, mrow, aq0, aq1, o0, o1, l0, l1, Pw);
        __syncthreads();
        cur ^= 1;
    }
    // Last step: even stream tile 2qb = MODE1; odd stream tile 2qb+1 = MODE2.
    if (st == 0)
        attn_step<1>(Kl[0][cur], Vl[0][cur], ws, quad, mrow, aq0, aq1, o0, o1, l0, l1, Pw);
    else
        attn_step<2>(Kl[1][cur], Vl[1][cur], ws, quad, mrow, aq0, aq1, o0, o1, l0, l1, Pw);

    // ---- in-block fp32 merge, conflict-free [slot][lane] layout ----
    __syncthreads();  // all waves done with K/V LDS
    f32x4* mo = (f32x4*)&Kl[0][0][0];   // 16 slots x 256 lanes x f32x4 = 64 KB
    float* ml = (float*)&Pl[0][0];      // 8 slots x 256 lanes x f32 = 8 KB
    int mlane = ws * 64 + lane;
    if (st == 1) {
#pragma unroll
        for (int d2 = 0; d2 < 8; ++d2) {
            mo[d2 * 256 + mlane] = o0[d2];
            mo[(d2 + 8) * 256 + mlane] = o1[d2];
        }
#pragma unroll
        for (int r = 0; r < 4; ++r) {
            ml[r * 256 + mlane] = l0[r];
            ml[(r + 4) * 256 + mlane] = l1[r];
        }
    }
    __syncthreads();
    if (st == 0) {
#pragma unroll
        for (int d2 = 0; d2 < 8; ++d2) {
            o0[d2] += mo[d2 * 256 + mlane];
            o1[d2] += mo[(d2 + 8) * 256 + mlane];
        }
#pragma unroll
        for (int r = 0; r < 4; ++r) {
            l0[r] += ml[r * 256 + mlane];
            l1[r] += ml[(r + 4) * 256 + mlane];
        }
#pragma unroll
        for (int hf = 0; hf < 2; ++hf) {
            f32x4* oo = hf ? o1 : o0;
            float* ll = hf ? l1 : l0;
            int srow0 = qb * 128 + hf * 64 + ws * 16 + quad * 4;
            float gv[4], il[4];
#pragma unroll
            for (int r = 0; r < 4; ++r) {
                gv[r] = gate[((size_t)b * 16 + h) * 2048 + srow0 + r];
                il[r] = 1.0f / fmaxf(ll[r], 1e-30f);
            }
#pragma unroll
            for (int d2 = 0; d2 < 8; ++d2)
#pragma unroll
                for (int r = 0; r < 4; ++r)
                    O[(size_t)(b * 2048 + srow0 + r) * 2048 + h * 128 + d2 * 16 + mrow] =
                        (__bf16)fin(oo[d2][r] * il[r] * gv[r]);
        }
    }
}

// ---------------------------------------------------------------------------
// Memory plan (ws <= 33,554,432 B; d_out doubles as scratch where safe).
//   d_out: xb[0,16.7M) + wqb[16.7M,29.36M) + gateb[29.36M,+256K) +
//          ropet[29.62M,+1M) -> Qb[0,16.7M) (over dead xb) -> out fp32
//   ws: qkv[0,25.2M) (Q+V cols only; K fused to Kb) -> attnb[0,16.7M) +
//       wob[16.7,25.2M) ; Kb[25.2,29.4M) / Vtb[29.4,33.5M) live thru attn.
// Launch graph (5): prep -> gemmQKV(+K-epi) -> mid -> attn(+wo cvt) -> gemmOut
// ---------------------------------------------------------------------------
extern "C" void kernel_launch(void* const* d_in, const int* in_sizes, int n_in,
                              void* d_out, int out_size, void* d_ws, size_t ws_size,
                              hipStream_t stream) {
    const float* x = (const float*)d_in[0];
    const float* w_qkv = (const float*)d_in[1];
    const float* q_norm_w = (const float*)d_in[2];
    const float* k_norm_w = (const float*)d_in[3];
    const float* w_gate = (const float*)d_in[4];
    const float* b_gate = (const float*)d_in[5];
    const float* w_o = (const float*)d_in[6];
    float* out = (float*)d_out;

    char* ws = (char*)d_ws;
    char* od = (char*)d_out;
    __bf16* xb = (__bf16*)(od);
    __bf16* wqb = (__bf16*)(od + 16777216);
    float* gateb = (float*)(od + 29360128);
    float2* ropet = (float2*)(od + 29622272);
    __bf16* Qb = (__bf16*)(od);
    __bf16* qkv = (__bf16*)(ws);
    __bf16* attnb = (__bf16*)(ws);
    __bf16* wob = (__bf16*)(ws + 16777216);
    __bf16* Kb = (__bf16*)(ws + 25165824);
    __bf16* Vtb = (__bf16*)(ws + 29360128);

    // prep: cvt x + gate [0,4096) + cvt w_qkv [4096,7168) + rope table [7168,7680)
    prep_kernel<<<7680, 256, 0, stream>>>(x, w_qkv, xb, wqb, w_gate, b_gate, gateb, ropet);
    // QKV GEMM: 256x256 tile, grid 12x16 = 192 blocks; fused K normrope -> Kb.
    gemm8p<8, 4, 1, __bf16><<<dim3(3072 / 256, 4096 / 256), 512, 0, stream>>>(
        xb, wqb, qkv, 4096, 3072, 2048, k_norm_w, ropet, Kb);
    // mid: Q normrope [0,16384) + vtrans [16384,16896)
    mid_kernel<<<16896, 256, 0, stream>>>(qkv, q_norm_w, ropet, Qb, Vtb);
    // attn [0,512) + w_o cvt tail [512,1536)
    attn_kernel<<<1536, 512, 0, stream>>>(Qb, Kb, Vtb, gateb, attnb, w_o, wob);
    // Output GEMM: 128x256 tile, grid 8x32 = 256 blocks (full chip).
    gemm8p<4, 4, 0, float><<<dim3(2048 / 256, 4096 / 128), 512, 0, stream>>>(
        attnb, wob, out, 4096, 2048, 2048, nullptr, nullptr, nullptr);
}

// Round 12
// 351.536 us; speedup vs baseline: 1.0273x; 1.0273x over previous
//
#include <hip/hip_runtime.h>

typedef __bf16 bf16x8 __attribute__((ext_vector_type(8)));
typedef float f32x4 __attribute__((ext_vector_type(4)));

typedef __attribute__((address_space(1))) void gvoid;
typedef __attribute__((address_space(3))) void lvoid;

__device__ __forceinline__ void gl_lds16(const void* g, void* l) {
    __builtin_amdgcn_global_load_lds((gvoid*)g, (lvoid*)l, 16, 0, 0);
}

// NaN/inf scrub for epilogues only.
__device__ __forceinline__ float fin(float v) {
    v = (v == v) ? v : 0.f;
    return fminf(fmaxf(v, -3.0e38f), 3.0e38f);
}

__device__ __forceinline__ bf16x8 cvt8(float4 a, float4 b) {
    bf16x8 r;
    r[0] = (__bf16)a.x; r[1] = (__bf16)a.y; r[2] = (__bf16)a.z; r[3] = (__bf16)a.w;
    r[4] = (__bf16)b.x; r[5] = (__bf16)b.y; r[6] = (__bf16)b.z; r[7] = (__bf16)b.w;
    return r;
}

__device__ __forceinline__ void cvt_range(const float* __restrict__ in,
                                          __bf16* __restrict__ out, int i) {
    const float4* p = (const float4*)in + (size_t)i * 2;
    ((bf16x8*)out)[i] = cvt8(p[0], p[1]);
}

// ---------------------------------------------------------------------------
// prep: fused cvt(x)+gate, cvt(w_qkv), rope table. (unchanged from round 8)
// ---------------------------------------------------------------------------
__global__ __launch_bounds__(256) void prep_kernel(const float* __restrict__ x,
                                                   const float* __restrict__ wqkv,
                                                   __bf16* __restrict__ xb,
                                                   __bf16* __restrict__ wqb,
                                                   const float* __restrict__ wg,
                                                   const float* __restrict__ bg,
                                                   float* __restrict__ gate,
                                                   float2* __restrict__ ropet) {
    __shared__ float gp[4][16];
    int bid = blockIdx.x, tid = threadIdx.x;
    if (bid < 4096) {
        // ---- one (b,s) row: cvt + gate ----
        int lane = tid & 63, wave = tid >> 6;
        const float4* xr = (const float4*)(x + (size_t)bid * 2048);
        float4 p0 = xr[tid * 2], p1 = xr[tid * 2 + 1];
        ((bf16x8*)xb)[bid * 256 + tid] = cvt8(p0, p1);
#pragma unroll
        for (int h = 0; h < 16; ++h) {
            const float4* wr = (const float4*)(wg + (size_t)h * 2048);
            float4 w0 = wr[tid * 2], w1 = wr[tid * 2 + 1];
            float acc = p0.x * w0.x + p0.y * w0.y + p0.z * w0.z + p0.w * w0.w +
                        p1.x * w1.x + p1.y * w1.y + p1.z * w1.z + p1.w * w1.w;
#pragma unroll
            for (int m = 1; m < 64; m <<= 1) acc += __shfl_xor(acc, m);
            if (lane == 0) gp[wave][h] = acc;
        }
        __syncthreads();
        if (tid < 16) {
            int s = bid & 2047, b = bid >> 11;
            float z = gp[0][tid] + gp[1][tid] + gp[2][tid] + gp[3][tid] + bg[tid];
            gate[((size_t)b * 16 + tid) * 2048 + s] = 1.f / (1.f + __expf(-z));
        }
        return;
    }
    if (bid < 7168) {
        cvt_range(wqkv, wqb, (bid - 4096) * 256 + tid);
        return;
    }
    // ---- rope table: idx = s*64 + d0 ----
    int idx = (bid - 7168) * 256 + tid;
    int s = idx >> 6, d0 = idx & 63;
    float freq = (float)s * __expf(-(float)d0 * (9.2103403719761836f / 64.0f));
    ropet[idx] = make_float2(cosf(freq), sinf(freq));
}

// ---------------------------------------------------------------------------
// 8-phase GEMM (m201 template) + T1 XCD swizzle + fused K-normrope epilogue.
// Round-10 conflict-free fragment swizzle retained (see comments there).
// ---------------------------------------------------------------------------
template <int WMT, int WNT, int EPI, typename TC>
__global__ __launch_bounds__(512) void gemm8p(const __bf16* __restrict__ A,
                                              const __bf16* __restrict__ B,
                                              TC* __restrict__ C,
                                              int M, int N, int K,
                                              const float* __restrict__ kw,
                                              const float2* __restrict__ ropet,
                                              __bf16* __restrict__ Kx) {
    constexpr int BM = WMT * 32;   // WARPS_M = 2
    constexpr int BN = WNT * 64;   // WARPS_N = 4
    constexpr int LA = BM / 128;   // gl_lds16 per thread per A half-tile
    constexpr int LB = BN / 128;
    constexpr int VMC = 2 * LA + LB;

    __shared__ __align__(16) __bf16 As[2][BM * 64];
    __shared__ __align__(16) __bf16 Bs[2][BN * 64];

    const int tid = threadIdx.x;
    const int lane = tid & 63, wave = tid >> 6;
    const int wm = wave >> 2, wn = wave & 3;
    const int quad = lane >> 4, mrow = lane & 15;

    // T1 bijective XCD swizzle (nwg % 8 == 0 for both instantiations).
    const int nbx = gridDim.x;
    const int nwg = nbx * gridDim.y;
    const int orig = (int)blockIdx.y * nbx + (int)blockIdx.x;
    const int wg = (orig & 7) * (nwg >> 3) + (orig >> 3);
    const size_t row0 = (size_t)(wg / nbx) * BM;
    const size_t col0 = (size_t)(wg % nbx) * BN;

    // Inverse-swizzled global source offsets for linear gl_lds staging.
    size_t sA[LA], sB[LB];
    int dA[LA], dB[LB];
#pragma unroll
    for (int c = 0; c < LA; ++c) {
        int q = c * 512 + tid;
        int a = q * 16;                       // linear LDS byte offset
        int p = (a >> 4) & 63;                // slot within 1024B subtile
        int rowl = (a >> 11) * 16 + (p >> 2);
        int g = (p & 3) ^ ((p >> 3) & 3);     // logical k-group at this slot
        int col = ((a >> 10) & 1) * 32 + g * 8;
        sA[c] = (size_t)rowl * K + col;
        dA[c] = q * 8;
    }
#pragma unroll
    for (int c = 0; c < LB; ++c) {
        int q = c * 512 + tid;
        int a = q * 16;
        int p = (a >> 4) & 63;
        int rowl = (a >> 11) * 16 + (p >> 2);
        int g = (p & 3) ^ ((p >> 3) & 3);
        int col = ((a >> 10) & 1) * 32 + g * 8;
        sB[c] = (size_t)rowl * K + col;
        dB[c] = q * 8;
    }

    const __bf16* Ag = A + row0 * K;
    const __bf16* Bg = B + col0 * K;

    f32x4 acc[WMT][WNT];
#pragma unroll
    for (int i = 0; i < WMT; ++i)
#pragma unroll
        for (int j = 0; j < WNT; ++j) acc[i][j] = (f32x4){0.f, 0.f, 0.f, 0.f};

    // Conflict-free per-lane ds_read base (slot = mrow*4 + quad^((mrow>>1)&3)).
    const int abase = mrow * 64 + ((quad ^ ((mrow >> 1) & 3)) * 16);

    bf16x8 af[WMT / 2][2], bf[WNT / 2][2];

#define STA8(buf, h, kt)                                                        \
    _Pragma("unroll") for (int c = 0; c < LA; ++c)                              \
        gl_lds16(Ag + (size_t)(h) * (BM / 2) * K + (size_t)(kt) * 64 + sA[c],   \
                 &As[buf][(h) * (BM / 2) * 64 + dA[c]])

#define STB8(buf, h, kt)                                                        \
    _Pragma("unroll") for (int c = 0; c < LB; ++c)                              \
        gl_lds16(Bg + (size_t)(h) * (BN / 2) * K + (size_t)(kt) * 64 + sB[c],   \
                 &Bs[buf][(h) * (BN / 2) * 64 + dB[c]])

#define LDA8(buf, mh)                                                           \
    _Pragma("unroll") for (int m2 = 0; m2 < WMT / 2; ++m2)                      \
    _Pragma("unroll") for (int s = 0; s < 2; ++s)                               \
        af[m2][s] = *(const bf16x8*)((const char*)&As[buf][0] +                 \
            ((((mh) * (WMT / 2) + m2) * 2 + wm) * 2 + s) * 1024 + abase)

#define LDB8(buf, nh)                                                           \
    _Pragma("unroll") for (int n2 = 0; n2 < WNT / 2; ++n2)                      \
    _Pragma("unroll") for (int s = 0; s < 2; ++s)                               \
        bf[n2][s] = *(const bf16x8*)((const char*)&Bs[buf][0] +                 \
            ((((nh) * (WNT / 2) + n2) * 4 + wn) * 2 + s) * 1024 + abase)

#define MMA8(mh, nh)                                                            \
    _Pragma("unroll") for (int m2 = 0; m2 < WMT / 2; ++m2)                      \
    _Pragma("unroll") for (int n2 = 0; n2 < WNT / 2; ++n2)                      \
    _Pragma("unroll") for (int s = 0; s < 2; ++s)                               \
        acc[(mh) * (WMT / 2) + m2][(nh) * (WNT / 2) + n2] =                     \
            __builtin_amdgcn_mfma_f32_16x16x32_bf16(                            \
                af[m2][s], bf[n2][s],                                           \
                acc[(mh) * (WMT / 2) + m2][(nh) * (WNT / 2) + n2], 0, 0, 0)

#define BAR8 __builtin_amdgcn_s_barrier()

#define WAITVM                                                                  \
    do {                                                                        \
        if constexpr (VMC == 6)                                                 \
            asm volatile("s_waitcnt vmcnt(6)" ::: "memory");                    \
        else                                                                    \
            asm volatile("s_waitcnt vmcnt(4)" ::: "memory");                    \
    } while (0)

#define PHASE_TAIL(mh, nh)                                                      \
    __builtin_amdgcn_s_barrier();                                               \
    asm volatile("s_waitcnt lgkmcnt(0)" ::: "memory");                          \
    __builtin_amdgcn_sched_barrier(0);                                          \
    __builtin_amdgcn_s_setprio(1);                                              \
    MMA8(mh, nh);                                                               \
    __builtin_amdgcn_s_setprio(0)

    const int NT = K / 64;

    STA8(0, 0, 0);
    STB8(0, 0, 0);
    STA8(0, 1, 0);
    STB8(0, 1, 0);
    STA8(1, 0, 1);
    STB8(1, 1, 1);
    STA8(1, 1, 1);
    WAITVM;
    BAR8;

    for (int i = 0; i < NT / 2; ++i) {
        const int u = 2 * i;
        const int k2 = (u + 2 < NT) ? u + 2 : NT - 1;
        const int k3 = (u + 3 < NT) ? u + 3 : NT - 1;
        // ---- tile u (buf0) ----
        LDA8(0, 0); LDB8(0, 0); STB8(1, 0, u + 1);
        PHASE_TAIL(0, 0); BAR8;
        LDB8(0, 1); STA8(0, 0, k2);
        PHASE_TAIL(0, 1); BAR8;
        LDA8(0, 1); STB8(0, 1, k2);
        PHASE_TAIL(1, 1); BAR8;
        LDB8(0, 0); STA8(0, 1, k2);
        PHASE_TAIL(1, 0); WAITVM; BAR8;
        // ---- tile u+1 (buf1) ----
        LDA8(1, 0); LDB8(1, 0); STB8(0, 0, k2);
        PHASE_TAIL(0, 0); BAR8;
        LDB8(1, 1); STA8(1, 0, k3);
        PHASE_TAIL(0, 1); BAR8;
        LDA8(1, 1); STB8(1, 1, k3);
        PHASE_TAIL(1, 1); BAR8;
        LDB8(1, 0); STA8(1, 1, k3);
        PHASE_TAIL(1, 0); WAITVM; BAR8;
    }
    asm volatile("s_waitcnt vmcnt(0)" ::: "memory");

#undef STA8
#undef STB8
#undef LDA8
#undef LDB8
#undef MMA8
#undef BAR8
#undef WAITVM
#undef PHASE_TAIL

    if constexpr (EPI) {
        int xblk = (int)(col0 >> 8);
        if (xblk == 8 || xblk == 9) {
            // ---- fused K normrope -> Kx (fp32-accurate rmsnorm) ----
            __syncthreads();  // LDS quiescent; reuse As for the reduce
            float* sums = (float*)&As[0][0];
            const int d0 = wn * 16 + mrow;
#pragma unroll
            for (int mt = 0; mt < WMT; ++mt)
#pragma unroll
                for (int t = 0; t < 2; ++t) {
                    f32x4 p;
#pragma unroll
                    for (int r = 0; r < 4; ++r)
                        p[r] = acc[mt][2 * t][r] * acc[mt][2 * t][r] +
                               acc[mt][2 * t + 1][r] * acc[mt][2 * t + 1][r];
#pragma unroll
                    for (int m = 1; m < 16; m <<= 1)
#pragma unroll
                        for (int r = 0; r < 4; ++r) p[r] += __shfl_xor(p[r], m);
                    if (mrow == 0) {
                        int idx = ((((wm * 8 + mt) * 4 + quad) * 2 + t) * 4 + wn) * 4;
#pragma unroll
                        for (int r = 0; r < 4; ++r) sums[idx + r] = p[r];
                    }
                }
            __syncthreads();
            float w1 = kw[d0], w2 = kw[d0 + 64];
#pragma unroll
            for (int mt = 0; mt < WMT; ++mt) {
                int rbase = (int)row0 + (mt * 2 + wm) * 16 + quad * 4;
#pragma unroll
                for (int t = 0; t < 2; ++t) {
                    int ib = (((wm * 8 + mt) * 4 + quad) * 2 + t) * 16;
                    f32x4 sv = *(const f32x4*)&sums[ib] + *(const f32x4*)&sums[ib + 4] +
                               *(const f32x4*)&sums[ib + 8] + *(const f32x4*)&sums[ib + 12];
                    int kvh = (xblk - 8) * 2 + t;
#pragma unroll
                    for (int r = 0; r < 4; ++r) {
                        int row = rbase + r;
                        int s_ = row & 2047, b_ = row >> 11;
                        float inv = rsqrtf(sv[r] * (1.0f / 128.0f) + 1e-5f);
                        float2 cs = ropet[s_ * 64 + d0];
                        float y1 = acc[mt][2 * t][r] * inv * w1;
                        float y2 = acc[mt][2 * t + 1][r] * inv * w2;
                        __bf16* dst = Kx + (((size_t)(b_ * 4 + kvh) * 2048 + s_) << 7);
                        dst[d0] = (__bf16)(y1 * cs.x - y2 * cs.y);
                        dst[d0 + 64] = (__bf16)(y1 * cs.y + y2 * cs.x);
                    }
                }
            }
            return;  // K never written to qkv
        }
    }

#pragma unroll
    for (int mt = 0; mt < WMT; ++mt)
#pragma unroll
        for (int nt = 0; nt < WNT; ++nt)
#pragma unroll
            for (int r = 0; r < 4; ++r) {
                size_t row = row0 + (mt * 2 + wm) * 16 + quad * 4 + r;
                size_t col = col0 + (nt * 4 + wn) * 16 + mrow;
                C[row * N + col] = (TC)fin(acc[mt][nt][r]);
            }
}

// ---------------------------------------------------------------------------
// mid: fused Q-normrope + vtrans. (unchanged from round 9)
// ---------------------------------------------------------------------------
#define SCALE_LOG2E 0.12751666797152713f

__global__ __launch_bounds__(256) void mid_kernel(const __bf16* __restrict__ qkv,
                                                  const float* __restrict__ qw,
                                                  const float2* __restrict__ ropet,
                                                  __bf16* __restrict__ Q,
                                                  __bf16* __restrict__ Vt) {
    __shared__ __align__(16) __bf16 tile[64][72];
    int bid = blockIdx.x, t = threadIdx.x;
    if (bid < 16384) {
        // ---- RMSNorm + RoPE, Q heads (pre-scaled for exp2 softmax) ----
        int wid = bid * 4 + (t >> 6);
        int lane = t & 63;
        int head = wid & 15;
        int bs = wid >> 4;
        int s = bs & 2047, b = bs >> 11;
        const __bf16* src = qkv + (size_t)bs * 3072 + head * 128;
        __bf16* dst = Q + ((size_t)(b * 16 + head) * 2048 + s) * 128;
        float x1 = (float)src[lane], x2 = (float)src[lane + 64];
        float ss = x1 * x1 + x2 * x2;
#pragma unroll
        for (int m = 1; m < 64; m <<= 1) ss += __shfl_xor(ss, m);
        float inv = rsqrtf(ss * (1.0f / 128.0f) + 1e-5f);
        float y1 = x1 * inv * qw[lane];
        float y2 = x2 * inv * qw[lane + 64];
        float2 cs = ropet[s * 64 + lane];
        dst[lane] = (__bf16)((y1 * cs.x - y2 * cs.y) * SCALE_LOG2E);
        dst[lane + 64] = (__bf16)((y1 * cs.y + y2 * cs.x) * SCALE_LOG2E);
        return;
    }
    // ---- V transpose ----
    int v = bid - 16384;
    int st0 = (v & 31) * 64;
    int dblk = (v >> 5) & 1;
    int bz = v >> 6;
    int b = bz >> 2, kv = bz & 3;
    const __bf16* src = qkv + (size_t)(b * 2048 + st0) * 3072 + 2560 + kv * 128 + dblk * 64;
#pragma unroll
    for (int it = 0; it < 2; ++it) {
        int row = it * 32 + (t >> 3);
        int ch = t & 7;
        *(bf16x8*)&tile[row][ch * 8] = *(const bf16x8*)(src + (size_t)row * 3072 + ch * 8);
    }
    __syncthreads();
    __bf16* dst = Vt + ((size_t)(b * 4 + kv) * 128 + dblk * 64) * 2048 + st0;
#pragma unroll
    for (int it = 0; it < 2; ++it) {
        int drow = it * 32 + (t >> 3);
        int sch = t & 7;
        bf16x8 vv;
#pragma unroll
        for (int j = 0; j < 8; ++j) vv[j] = tile[sch * 8 + j][drow];
        *(bf16x8*)(dst + (size_t)drow * 2048 + sch * 8) = vv;
    }
}

// ---------------------------------------------------------------------------
// Flash attention v9 = v8 structure with the P-bounce cost attacked:
//  (a) P-buffer XOR swizzle: element e stored at e ^ (((e>>7)&1)<<4).
//      Write side: XORs chunk-bit1 with hi=(k>>3)&1 -> the 8 (hi,quad)
//      writer groups per (jt,r) drop from 4-way to 2-way (free) bank
//      conflict. Read side: same involution = addr ^ ((quad&1)<<4 elems);
//      ds_read_b128 lanes stay mrow^const -> conflict-free. Both sides of
//      the involution applied (rule #21).
//  (b) Row-sums via MFMA-ones: l_frag = mfma(ap[ks], ONES, l_frag). The
//      16x16x32 C-layout (row = quad*4+r) lands sums in exactly the l_i[r]
//      register layout. Removes 32 shfl_xor + 32 VALU adds per step for 4
//      MFMA on the idle matrix pipe; l and O now both derive from the same
//      bf16-rounded P (more self-consistent than the old fp32 shfl sums).
// ---------------------------------------------------------------------------
#define FIXED_M 20.0f

#define MFMA16(a, b, c) __builtin_amdgcn_mfma_f32_16x16x32_bf16(a, b, c, 0, 0, 0)

__device__ __forceinline__ int pswz(int e) { return e ^ (((e >> 7) & 1) << 4); }

template <int MODE>  // 0: both full; 1: h0 diag + h1 full; 2: h1 diag only
__device__ __forceinline__ void attn_step(const __bf16* Kl, const __bf16* Vl,
                                          int ws, int quad, int mrow,
                                          const bf16x8* aq0, const bf16x8* aq1,
                                          f32x4* o0, f32x4* o1,
                                          f32x4& lf0, f32x4& lf1,
                                          __bf16* Pw) {
    bf16x8 ones;
#pragma unroll
    for (int i = 0; i < 8; ++i) ones[i] = (__bf16)1.0f;

    f32x4 sc0[4], sc1[4];
    __builtin_amdgcn_s_setprio(1);
#pragma unroll
    for (int jt = 0; jt < 4; ++jt) {
        f32x4 s0 = (f32x4){0.f, 0.f, 0.f, 0.f};
        f32x4 s1 = (f32x4){0.f, 0.f, 0.f, 0.f};
#pragma unroll
        for (int dt = 0; dt < 4; ++dt) {
            bf16x8 bk = *(const bf16x8*)&Kl[((dt * 4 + quad) * 64 + jt * 16 + mrow) * 8];
            if (MODE < 2) s0 = MFMA16(aq0[dt], bk, s0);
            s1 = MFMA16(aq1[dt], bk, s1);
        }
        sc0[jt] = s0;
        sc1[jt] = s1;
    }
    __builtin_amdgcn_s_setprio(0);

    if (MODE == 1) {
        int rloc = ws * 16 + quad * 4;
#pragma unroll
        for (int jt = 0; jt < 4; ++jt)
#pragma unroll
            for (int r = 0; r < 4; ++r)
                if (jt * 16 + mrow > rloc + r) sc0[jt][r] = -1e30f;
    }
    if (MODE == 2) {
        int rloc = ws * 16 + quad * 4;
#pragma unroll
        for (int jt = 0; jt < 4; ++jt)
#pragma unroll
            for (int r = 0; r < 4; ++r)
                if (jt * 16 + mrow > rloc + r) sc1[jt][r] = -1e30f;
    }

    // Streaming softmax through the SHARED per-wave P buffer (h0 then h1;
    // same-wave DS ops execute in order, so the WAR on Pw is safe).
    const int rb0 = pswz(((0 * 4 + quad) * 16 + mrow) * 8);
    const int rb1 = pswz(((1 * 4 + quad) * 16 + mrow) * 8);
    bf16x8 ap0[2], ap1[2];
    if (MODE < 2) {
#pragma unroll
        for (int jt = 0; jt < 4; ++jt)
#pragma unroll
            for (int r = 0; r < 4; ++r) {
                float pv = exp2f(sc0[jt][r] - FIXED_M);
                int k = jt * 16 + mrow;
                Pw[pswz(((k >> 3) * 16 + quad * 4 + r) * 8 + (k & 7))] = (__bf16)pv;
            }
        ap0[0] = *(const bf16x8*)&Pw[rb0];
        ap0[1] = *(const bf16x8*)&Pw[rb1];
        lf0 = MFMA16(ap0[0], ones, lf0);
        lf0 = MFMA16(ap0[1], ones, lf0);
    }
#pragma unroll
    for (int jt = 0; jt < 4; ++jt)
#pragma unroll
        for (int r = 0; r < 4; ++r) {
            float pv = exp2f(sc1[jt][r] - FIXED_M);
            int k = jt * 16 + mrow;
            Pw[pswz(((k >> 3) * 16 + quad * 4 + r) * 8 + (k & 7))] = (__bf16)pv;
        }
    ap1[0] = *(const bf16x8*)&Pw[rb0];
    ap1[1] = *(const bf16x8*)&Pw[rb1];
    lf1 = MFMA16(ap1[0], ones, lf1);
    lf1 = MFMA16(ap1[1], ones, lf1);

    __builtin_amdgcn_s_setprio(1);
#pragma unroll
    for (int d2 = 0; d2 < 8; ++d2)
#pragma unroll
        for (int ks = 0; ks < 2; ++ks) {
            bf16x8 bv = *(const bf16x8*)&Vl[((ks * 4 + quad) * 128 + d2 * 16 + mrow) * 8];
            if (MODE < 2) o0[d2] = MFMA16(ap0[ks], bv, o0[d2]);
            o1[d2] = MFMA16(ap1[ks], bv, o1[d2]);
        }
    __builtin_amdgcn_s_setprio(0);
}

__global__ __launch_bounds__(512, 2) void attn_kernel(const __bf16* __restrict__ Q,
                                                      const __bf16* __restrict__ Kx,
                                                      const __bf16* __restrict__ Vt,
                                                      const float* __restrict__ gate,
                                                      __bf16* __restrict__ O,
                                                      const float* __restrict__ wo,
                                                      __bf16* __restrict__ wob) {
    __shared__ __align__(16) __bf16 Kl[2][2][64 * 128];  // [stream][buf]
    __shared__ __align__(16) __bf16 Vl[2][2][128 * 64];  // [stream][buf]
    __shared__ __align__(16) __bf16 Pl[8][1024];
    int tid = threadIdx.x, lane = tid & 63, wave = tid >> 6;

    if (blockIdx.x >= 512) {
        // ---- w_o cvt tail: backfills CUs as attn blocks drain ----
        cvt_range(wo, wob, ((int)blockIdx.x - 512) * 512 + tid);
        return;
    }

    int ws = wave & 3, st = wave >> 2;  // row-group, stream
    int quad = lane >> 4, mrow = lane & 15;
    __bf16* Pw = &Pl[wave][0];

    int idx = blockIdx.x;
    int qb = 15 - (idx >> 5);  // longest items dispatch first (backfill)
    int h = idx & 15, b = (idx >> 4) & 1;
    int kvh = h >> 2;

    // Staging: threads 0-255 stage the even-stream tile, 256-511 the odd.
    int sst = tid >> 8, lt = tid & 255;
    const __bf16* kbase = Kx + (size_t)(b * 4 + kvh) * 2048 * 128 + (lt & 63) * 128 + (lt >> 6) * 8;
    const __bf16* vbase = Vt + (size_t)(b * 4 + kvh) * 128 * 2048 + (lt & 127) * 2048 + (lt >> 7) * 8;
    int ldst = lt * 8;

    auto STAGE = [&](int buf, int tile) {
        const __bf16* kp = kbase + (size_t)tile * 8192;
        const __bf16* vp = vbase + (size_t)tile * 64;
#pragma unroll
        for (int c = 0; c < 4; ++c) gl_lds16(kp + 32 * c, &Kl[sst][buf][ldst + 2048 * c]);
#pragma unroll
        for (int c = 0; c < 4; ++c) gl_lds16(vp + 16 * c, &Vl[sst][buf][ldst + 2048 * c]);
    };

    STAGE(0, sst);  // even stream: tile 0; odd stream: tile 1

    const __bf16* Qh = Q + ((size_t)(b * 16 + h) * 2048 + qb * 128 + ws * 16 + mrow) * 128;
    bf16x8 aq0[4], aq1[4];
#pragma unroll
    for (int dt = 0; dt < 4; ++dt) {
        aq0[dt] = *(const bf16x8*)(Qh + dt * 32 + quad * 8);
        aq1[dt] = *(const bf16x8*)(Qh + 8192 + dt * 32 + quad * 8);
    }

    f32x4 o0[8], o1[8];
#pragma unroll
    for (int d2 = 0; d2 < 8; ++d2) {
        o0[d2] = (f32x4){0.f, 0.f, 0.f, 0.f};
        o1[d2] = (f32x4){0.f, 0.f, 0.f, 0.f};
    }
    f32x4 lf0 = (f32x4){0.f, 0.f, 0.f, 0.f}, lf1 = (f32x4){0.f, 0.f, 0.f, 0.f};

    __syncthreads();  // tiles 0,1 visible (barrier drains gl_lds)

    int cur = 0;
    for (int kt = 0; kt < qb; ++kt) {
        STAGE(cur ^ 1, 2 * (kt + 1) + sst);  // prefetch both streams' next
        attn_step<0>(Kl[st][cur], Vl[st][cur], ws, quad, mrow, aq0, aq1, o0, o1, lf0, lf1, Pw);
        __syncthreads();
        cur ^= 1;
    }
    // Last step: even stream tile 2qb = MODE1; odd stream tile 2qb+1 = MODE2.
    if (st == 0)
        attn_step<1>(Kl[0][cur], Vl[0][cur], ws, quad, mrow, aq0, aq1, o0, o1, lf0, lf1, Pw);
    else
        attn_step<2>(Kl[1][cur], Vl[1][cur], ws, quad, mrow, aq0, aq1, o0, o1, lf0, lf1, Pw);

    // ---- in-block fp32 merge, conflict-free [slot][lane] layout ----
    __syncthreads();  // all waves done with K/V LDS
    f32x4* mo = (f32x4*)&Kl[0][0][0];   // 16 slots x 256 lanes x f32x4 = 64 KB
    float* ml = (float*)&Pl[0][0];      // 8 slots x 256 lanes x f32 = 8 KB
    int mlane = ws * 64 + lane;
    if (st == 1) {
#pragma unroll
        for (int d2 = 0; d2 < 8; ++d2) {
            mo[d2 * 256 + mlane] = o0[d2];
            mo[(d2 + 8) * 256 + mlane] = o1[d2];
        }
#pragma unroll
        for (int r = 0; r < 4; ++r) {
            ml[r * 256 + mlane] = lf0[r];
            ml[(r + 4) * 256 + mlane] = lf1[r];
        }
    }
    __syncthreads();
    if (st == 0) {
#pragma unroll
        for (int d2 = 0; d2 < 8; ++d2) {
            o0[d2] += mo[d2 * 256 + mlane];
            o1[d2] += mo[(d2 + 8) * 256 + mlane];
        }
#pragma unroll
        for (int r = 0; r < 4; ++r) {
            lf0[r] += ml[r * 256 + mlane];
            lf1[r] += ml[(r + 4) * 256 + mlane];
        }
#pragma unroll
        for (int hf = 0; hf < 2; ++hf) {
            f32x4* oo = hf ? o1 : o0;
            f32x4 ll = hf ? lf1 : lf0;
            int srow0 = qb * 128 + hf * 64 + ws * 16 + quad * 4;
            float gv[4], il[4];
#pragma unroll
            for (int r = 0; r < 4; ++r) {
                gv[r] = gate[((size_t)b * 16 + h) * 2048 + srow0 + r];
                il[r] = 1.0f / fmaxf(ll[r], 1e-30f);
            }
#pragma unroll
            for (int d2 = 0; d2 < 8; ++d2)
#pragma unroll
                for (int r = 0; r < 4; ++r)
                    O[(size_t)(b * 2048 + srow0 + r) * 2048 + h * 128 + d2 * 16 + mrow] =
                        (__bf16)fin(oo[d2][r] * il[r] * gv[r]);
        }
    }
}

// ---------------------------------------------------------------------------
// Memory plan (ws <= 33,554,432 B; d_out doubles as scratch where safe).
//   d_out: xb[0,16.7M) + wqb[16.7M,29.36M) + gateb[29.36M,+256K) +
//          ropet[29.62M,+1M) -> Qb[0,16.7M) (over dead xb) -> out fp32
//   ws: qkv[0,25.2M) (Q+V cols only; K fused to Kb) -> attnb[0,16.7M) +
//       wob[16.7,25.2M) ; Kb[25.2,29.4M) / Vtb[29.4,33.5M) live thru attn.
// Launch graph (5): prep -> gemmQKV(+K-epi) -> mid -> attn(+wo cvt) -> gemmOut
// ---------------------------------------------------------------------------
extern "C" void kernel_launch(void* const* d_in, const int* in_sizes, int n_in,
                              void* d_out, int out_size, void* d_ws, size_t ws_size,
                              hipStream_t stream) {
    const float* x = (const float*)d_in[0];
    const float* w_qkv = (const float*)d_in[1];
    const float* q_norm_w = (const float*)d_in[2];
    const float* k_norm_w = (const float*)d_in[3];
    const float* w_gate = (const float*)d_in[4];
    const float* b_gate = (const float*)d_in[5];
    const float* w_o = (const float*)d_in[6];
    float* out = (float*)d_out;

    char* ws = (char*)d_ws;
    char* od = (char*)d_out;
    __bf16* xb = (__bf16*)(od);
    __bf16* wqb = (__bf16*)(od + 16777216);
    float* gateb = (float*)(od + 29360128);
    float2* ropet = (float2*)(od + 29622272);
    __bf16* Qb = (__bf16*)(od);
    __bf16* qkv = (__bf16*)(ws);
    __bf16* attnb = (__bf16*)(ws);
    __bf16* wob = (__bf16*)(ws + 16777216);
    __bf16* Kb = (__bf16*)(ws + 25165824);
    __bf16* Vtb = (__bf16*)(ws + 29360128);

    // prep: cvt x + gate [0,4096) + cvt w_qkv [4096,7168) + rope table [7168,7680)
    prep_kernel<<<7680, 256, 0, stream>>>(x, w_qkv, xb, wqb, w_gate, b_gate, gateb, ropet);
    // QKV GEMM: 256x256 tile, grid 12x16 = 192 blocks; fused K normrope -> Kb.
    gemm8p<8, 4, 1, __bf16><<<dim3(3072 / 256, 4096 / 256), 512, 0, stream>>>(
        xb, wqb, qkv, 4096, 3072, 2048, k_norm_w, ropet, Kb);
    // mid: Q normrope [0,16384) + vtrans [16384,16896)
    mid_kernel<<<16896, 256, 0, stream>>>(qkv, q_norm_w, ropet, Qb, Vtb);
    // attn [0,512) + w_o cvt tail [512,1536)
    attn_kernel<<<1536, 512, 0, stream>>>(Qb, Kb, Vtb, gateb, attnb, w_o, wob);
    // Output GEMM: 128x256 tile, grid 8x32 = 256 blocks (full chip).
    gemm8p<4, 4, 0, float><<<dim3(2048 / 256, 4096 / 128), 512, 0, stream>>>(
        attnb, wob, out, 4096, 2048, 2048, nullptr, nullptr, nullptr);
}